// Round 3
// baseline (432.940 us; speedup 1.0000x reference)
//
#include <hip/hip_runtime.h>

#define N_SUP 4096
#define N_QRY 8192
#define IN_DIM 784
#define EMB 512
#define NCLS 64
#define M_TOT (N_SUP + N_QRY)

typedef _Float16 f16;
typedef _Float16 f16x8 __attribute__((ext_vector_type(8)));
typedef float f32x4 __attribute__((ext_vector_type(4)));

// load 8 consecutive fp32 and convert to f16x8
static __device__ __forceinline__ f16x8 cvt8(const float* p) {
    float4 a = *(const float4*)p;
    float4 b = *(const float4*)(p + 4);
    f16x8 v;
    v[0] = (f16)a.x; v[1] = (f16)a.y; v[2] = (f16)a.z; v[3] = (f16)a.w;
    v[4] = (f16)b.x; v[5] = (f16)b.y; v[6] = (f16)b.z; v[7] = (f16)b.w;
    return v;
}

// ---- prep: W (784x512 fp32) -> WT (512x784 f16), WT[n][k] = W[k][n] ----
__global__ void prep_wt(const float* __restrict__ W, f16* __restrict__ WT) {
    int idx = blockIdx.x * 256 + threadIdx.x;
    if (idx >= EMB * IN_DIM) return;
    int n = idx / IN_DIM, k = idx - n * IN_DIM;
    WT[idx] = (f16)W[k * EMB + n];
}

// ---- prep: one-hot labels (4096x64 fp32) -> argmax index ----
__global__ void prep_lbl(const float* __restrict__ lab, int* __restrict__ lbl) {
    int s = blockIdx.x * 256 + threadIdx.x;
    if (s >= N_SUP) return;
    int best = 0; float bv = -1e30f;
    for (int c = 0; c < NCLS; ++c) {
        float v = lab[s * NCLS + c];
        if (v > bv) { bv = v; best = c; }
    }
    lbl[s] = best;
}

// ---- encode: E[i] = X[i] @ W + b for 12288 rows; f16 MFMA, fp32 row norms.
__global__ __launch_bounds__(256) void encode(
    const float* __restrict__ sup, const float* __restrict__ qry,
    const f16* __restrict__ WT, const float* __restrict__ bias,
    f16* __restrict__ E, float* __restrict__ norms)
{
    __shared__ __align__(16) f16 Xs[64][40];
    __shared__ __align__(16) f16 Ws[64][40];
    const int tid = threadIdx.x;
    const int w = tid >> 6, lane = tid & 63;
    const int m0 = blockIdx.x * 64;
    const int n0 = blockIdx.y * 64;

    f32x4 acc[4];
#pragma unroll
    for (int nb = 0; nb < 4; ++nb) acc[nb] = (f32x4){0.f, 0.f, 0.f, 0.f};

    const int sr = tid >> 2;          // staging row 0..63
    const int sc = (tid & 3) * 8;     // staging k-offset 0/8/16/24
    const float* xrow;
    {
        int g = m0 + sr;
        xrow = (g < N_SUP) ? (sup + (size_t)g * IN_DIM)
                           : (qry + (size_t)(g - N_SUP) * IN_DIM);
    }
    const f16* wrow = WT + (size_t)(n0 + sr) * IN_DIM;

    const int q = lane >> 4, c16 = lane & 15;
    const int ar = w * 16 + c16;      // A-frag row within tile
    const int koff = q * 8;           // A/B-frag k offset within 32-chunk

    for (int k0 = 0; k0 < IN_DIM; k0 += 32) {
        __syncthreads();
        if (k0 + sc + 8 <= IN_DIM) {
            *(f16x8*)&Xs[sr][sc] = cvt8(xrow + k0 + sc);
            *(f16x8*)&Ws[sr][sc] = *(const f16x8*)(wrow + k0 + sc);
        } else {
            f16x8 z = (f16x8){0,0,0,0,0,0,0,0};
            *(f16x8*)&Xs[sr][sc] = z;
            *(f16x8*)&Ws[sr][sc] = z;
        }
        __syncthreads();
        f16x8 a = *(const f16x8*)&Xs[ar][koff];
#pragma unroll
        for (int nb = 0; nb < 4; ++nb) {
            f16x8 b = *(const f16x8*)&Ws[nb * 16 + c16][koff];
            acc[nb] = __builtin_amdgcn_mfma_f32_16x16x32_f16(a, b, acc[nb], 0, 0, 0);
        }
    }

    // epilogue: bias, store f16, accumulate norms
    float nrm[4] = {0.f, 0.f, 0.f, 0.f};
#pragma unroll
    for (int nb = 0; nb < 4; ++nb) {
        int col = n0 + nb * 16 + c16;
        float bv = bias[col];
#pragma unroll
        for (int r = 0; r < 4; ++r) {
            int row = m0 + w * 16 + q * 4 + r;
            float v = acc[nb][r] + bv;
            E[(size_t)row * EMB + col] = (f16)v;
            nrm[r] += v * v;
        }
    }
#pragma unroll
    for (int r = 0; r < 4; ++r) {
        float v = nrm[r];
        v += __shfl_xor(v, 1); v += __shfl_xor(v, 2);
        v += __shfl_xor(v, 4); v += __shfl_xor(v, 8);
        if (c16 == 0) atomicAdd(&norms[m0 + w * 16 + q * 4 + r], v);
    }
}

// ---- fused: distances -> exp -> label scatter + denominator (no-max softmax:
// d = -sqrt(d2) is always in [-75, 0], so exp never overflows/underflows)
__global__ __launch_bounds__(256) void attn(
    const f16* __restrict__ E, const float* __restrict__ norms,
    const int* __restrict__ lbl, float* __restrict__ Num, float* __restrict__ Den)
{
    __shared__ float NumS[64][NCLS];
    const int tid = threadIdx.x;
    const int w = tid >> 6, lane = tid & 63;
    const int qt = blockIdx.x >> 2, ss = blockIdx.x & 3;
    const int q = lane >> 4, c16 = lane & 15;

    for (int i = tid; i < 64 * NCLS; i += 256) ((float*)NumS)[i] = 0.f;
    __syncthreads();

    // preload Q fragments for this wave's 16 rows (A-layout: m = lane&15)
    const f16* qbase = E + (size_t)(N_SUP + qt * 64 + w * 16 + c16) * EMB + q * 8;
    f16x8 qf[16];
#pragma unroll
    for (int ks = 0; ks < 16; ++ks) qf[ks] = *(const f16x8*)(qbase + ks * 32);
    float q2[4];
#pragma unroll
    for (int r = 0; r < 4; ++r) q2[r] = norms[N_SUP + qt * 64 + w * 16 + q * 4 + r];

    float den[4] = {0.f, 0.f, 0.f, 0.f};
    const int s_begin = ss * (N_SUP / 4);

    for (int s0 = s_begin; s0 < s_begin + N_SUP / 4; s0 += 64) {
        f32x4 acc[4];
#pragma unroll
        for (int nb = 0; nb < 4; ++nb) {
            acc[nb] = (f32x4){0.f, 0.f, 0.f, 0.f};
            const f16* sbase = E + (size_t)(s0 + nb * 16 + c16) * EMB + q * 8;
#pragma unroll
            for (int ks = 0; ks < 16; ++ks) {
                f16x8 b = *(const f16x8*)(sbase + ks * 32);
                acc[nb] = __builtin_amdgcn_mfma_f32_16x16x32_f16(qf[ks], b, acc[nb], 0, 0, 0);
            }
        }
#pragma unroll
        for (int nb = 0; nb < 4; ++nb) {
            int col = s0 + nb * 16 + c16;
            float s2 = norms[col];
            int lb = lbl[col];
#pragma unroll
            for (int r = 0; r < 4; ++r) {
                float d2 = fmaxf(q2[r] + s2 - 2.f * acc[nb][r], 0.f);
                float e = __expf(-sqrtf(d2));
                den[r] += e;
                atomicAdd(&NumS[w * 16 + q * 4 + r][lb], e);
            }
        }
    }

#pragma unroll
    for (int r = 0; r < 4; ++r) {
        float v = den[r];
        v += __shfl_xor(v, 1); v += __shfl_xor(v, 2);
        v += __shfl_xor(v, 4); v += __shfl_xor(v, 8);
        if (c16 == 0) atomicAdd(&Den[qt * 64 + w * 16 + q * 4 + r], v);
    }
    __syncthreads();
    for (int i = tid; i < 64 * NCLS; i += 256)
        atomicAdd(&Num[(size_t)qt * 64 * NCLS + i], ((float*)NumS)[i]);
}

// ---- finalize: out = fp32(Num/Den) ----
__global__ void finalize(const float* __restrict__ Num, const float* __restrict__ Den,
                         float* __restrict__ out) {
    int i = blockIdx.x * 256 + threadIdx.x;
    if (i >= N_QRY * NCLS) return;
    out[i] = Num[i] / Den[i >> 6];
}

extern "C" void kernel_launch(void* const* d_in, const int* in_sizes, int n_in,
                              void* d_out, int out_size, void* d_ws, size_t ws_size,
                              hipStream_t stream) {
    (void)in_sizes; (void)n_in; (void)out_size; (void)ws_size;
    const float* sup  = (const float*)d_in[0];
    const float* qry  = (const float*)d_in[1];
    const float* lab  = (const float*)d_in[2];
    const float* Wenc = (const float*)d_in[3];
    const float* benc = (const float*)d_in[4];
    float* out = (float*)d_out;

    char* ws = (char*)d_ws;
    size_t off = 0;
    f16* WT = (f16*)(ws + off);        off += (size_t)EMB * IN_DIM * 2;   // 802816
    f16* E  = (f16*)(ws + off);        off += (size_t)M_TOT * EMB * 2;    // 12582912
    float* norms = (float*)(ws + off); off += (size_t)M_TOT * 4;          // 49152
    int* lbl = (int*)(ws + off);       off += (size_t)N_SUP * 4;          // 16384
    float* Num = (float*)(ws + off);   off += (size_t)N_QRY * NCLS * 4;   // 2097152
    float* Den = (float*)(ws + off);   off += (size_t)N_QRY * 4;          // 32768

    hipMemsetAsync(norms, 0, (size_t)M_TOT * 4, stream);
    hipMemsetAsync(Num, 0, (size_t)N_QRY * NCLS * 4 + (size_t)N_QRY * 4, stream);

    prep_wt<<<(EMB * IN_DIM + 255) / 256, 256, 0, stream>>>(Wenc, WT);
    prep_lbl<<<(N_SUP + 255) / 256, 256, 0, stream>>>(lab, lbl);
    encode<<<dim3(M_TOT / 64, EMB / 64), 256, 0, stream>>>(sup, qry, WT, benc, E, norms);
    attn<<<512, 256, 0, stream>>>(E, norms, lbl, Num, Den);
    finalize<<<(N_QRY * NCLS + 255) / 256, 256, 0, stream>>>(Num, Den, out);
}

// Round 4
// 346.530 us; speedup vs baseline: 1.2494x; 1.2494x over previous
//
#include <hip/hip_runtime.h>

#define N_SUP 4096
#define N_QRY 8192
#define IN_DIM 784
#define EMB 512
#define NCLS 64
#define M_TOT (N_SUP + N_QRY)

typedef _Float16 f16;
typedef _Float16 f16x8 __attribute__((ext_vector_type(8)));
typedef float f32x4 __attribute__((ext_vector_type(4)));

// load 8 consecutive fp32 and convert to f16x8
static __device__ __forceinline__ f16x8 cvt8(const float* p) {
    float4 a = *(const float4*)p;
    float4 b = *(const float4*)(p + 4);
    f16x8 v;
    v[0] = (f16)a.x; v[1] = (f16)a.y; v[2] = (f16)a.z; v[3] = (f16)a.w;
    v[4] = (f16)b.x; v[5] = (f16)b.y; v[6] = (f16)b.z; v[7] = (f16)b.w;
    return v;
}

// ---- prep: W (784x512 fp32) -> WT (512x784 f16), LDS-tiled transpose ----
__global__ __launch_bounds__(256) void prep_wt(const float* __restrict__ W,
                                               f16* __restrict__ WT) {
    __shared__ float T[32][33];
    const int k0 = blockIdx.x * 32, n0 = blockIdx.y * 32;
    const int tx = threadIdx.x & 31, ty = threadIdx.x >> 5;  // ty: 0..7
#pragma unroll
    for (int i = 0; i < 4; ++i) {
        int k = k0 + ty + i * 8;
        T[ty + i * 8][tx] = (k < IN_DIM) ? W[(size_t)k * EMB + n0 + tx] : 0.f;
    }
    __syncthreads();
#pragma unroll
    for (int i = 0; i < 4; ++i) {
        int n = n0 + ty + i * 8;
        int k = k0 + tx;
        if (k < IN_DIM) WT[(size_t)n * IN_DIM + k] = (f16)T[tx][ty + i * 8];
    }
}

// ---- prep: one-hot labels (4096x64 fp32) -> argmax index ----
__global__ void prep_lbl(const float* __restrict__ lab, int* __restrict__ lbl) {
    int s = blockIdx.x * 256 + threadIdx.x;
    if (s >= N_SUP) return;
    int best = 0; float bv = -1e30f;
    for (int c = 0; c < NCLS; ++c) {
        float v = lab[s * NCLS + c];
        if (v > bv) { bv = v; best = c; }
    }
    lbl[s] = best;
}

// ---- encode: E = X @ W + b, 128x128 tile, 4 waves, 2x8 frag outer product.
__global__ __launch_bounds__(256) void encode(
    const float* __restrict__ sup, const float* __restrict__ qry,
    const f16* __restrict__ WT, const float* __restrict__ bias,
    f16* __restrict__ E, float* __restrict__ norms)
{
    __shared__ __align__(16) f16 Xs[128][40];
    __shared__ __align__(16) f16 Ws[128][40];
    const int tid = threadIdx.x;
    const int w = tid >> 6, lane = tid & 63;
    const int q = lane >> 4, c16 = lane & 15;
    const int m0 = blockIdx.x * 128, n0 = blockIdx.y * 128;

    f32x4 acc[2][8];
#pragma unroll
    for (int h = 0; h < 2; ++h)
#pragma unroll
        for (int nb = 0; nb < 8; ++nb) acc[h][nb] = (f32x4){0.f, 0.f, 0.f, 0.f};

    const int srow = tid >> 2;            // 0..63
    const int koff = (tid & 3) * 8;       // 0,8,16,24
    const float *xrow0, *xrow1;
    {
        int g0 = m0 + srow, g1 = m0 + srow + 64;
        xrow0 = (g0 < N_SUP) ? sup + (size_t)g0 * IN_DIM : qry + (size_t)(g0 - N_SUP) * IN_DIM;
        xrow1 = (g1 < N_SUP) ? sup + (size_t)g1 * IN_DIM : qry + (size_t)(g1 - N_SUP) * IN_DIM;
    }
    const f16* wrow0 = WT + (size_t)(n0 + srow) * IN_DIM;
    const f16* wrow1 = wrow0 + (size_t)64 * IN_DIM;

    for (int k0 = 0; k0 < IN_DIM; k0 += 32) {
        __syncthreads();
        if (k0 + koff + 8 <= IN_DIM) {
            *(f16x8*)&Xs[srow][koff]      = cvt8(xrow0 + k0 + koff);
            *(f16x8*)&Xs[srow + 64][koff] = cvt8(xrow1 + k0 + koff);
            *(f16x8*)&Ws[srow][koff]      = *(const f16x8*)(wrow0 + k0 + koff);
            *(f16x8*)&Ws[srow + 64][koff] = *(const f16x8*)(wrow1 + k0 + koff);
        } else {
            f16x8 z = (f16x8){0,0,0,0,0,0,0,0};
            *(f16x8*)&Xs[srow][koff]      = z;
            *(f16x8*)&Xs[srow + 64][koff] = z;
            *(f16x8*)&Ws[srow][koff]      = z;
            *(f16x8*)&Ws[srow + 64][koff] = z;
        }
        __syncthreads();
        f16x8 a0 = *(const f16x8*)&Xs[w * 16 + c16][q * 8];
        f16x8 a1 = *(const f16x8*)&Xs[64 + w * 16 + c16][q * 8];
#pragma unroll
        for (int nb = 0; nb < 8; ++nb) {
            f16x8 b = *(const f16x8*)&Ws[nb * 16 + c16][q * 8];
            acc[0][nb] = __builtin_amdgcn_mfma_f32_16x16x32_f16(a0, b, acc[0][nb], 0, 0, 0);
            acc[1][nb] = __builtin_amdgcn_mfma_f32_16x16x32_f16(a1, b, acc[1][nb], 0, 0, 0);
        }
    }

    float nrm[2][4] = {};
#pragma unroll
    for (int nb = 0; nb < 8; ++nb) {
        int col = n0 + nb * 16 + c16;
        float bv = bias[col];
#pragma unroll
        for (int h = 0; h < 2; ++h) {
#pragma unroll
            for (int r = 0; r < 4; ++r) {
                int row = m0 + h * 64 + w * 16 + q * 4 + r;
                float v = acc[h][nb][r] + bv;
                E[(size_t)row * EMB + col] = (f16)v;
                nrm[h][r] += v * v;
            }
        }
    }
#pragma unroll
    for (int h = 0; h < 2; ++h)
#pragma unroll
        for (int r = 0; r < 4; ++r) {
            float v = nrm[h][r];
            v += __shfl_xor(v, 1); v += __shfl_xor(v, 2);
            v += __shfl_xor(v, 4); v += __shfl_xor(v, 8);
            if (c16 == 0) atomicAdd(&norms[m0 + h * 64 + w * 16 + q * 4 + r], v);
        }
}

// ---- fused attn: q-tile 128 (2 A-frags/wave), S staged in LDS in 128-k chunks.
__global__ __launch_bounds__(256) void attn(
    const f16* __restrict__ E, const float* __restrict__ norms,
    const int* __restrict__ lbl, float* __restrict__ Num, float* __restrict__ Den)
{
    __shared__ __align__(16) f16 Ss[64][136];
    __shared__ float NumS[128][NCLS];
    const int tid = threadIdx.x;
    const int w = tid >> 6, lane = tid & 63;
    const int q = lane >> 4, c16 = lane & 15;
    const int qt = blockIdx.x;            // 64 q-tiles of 128
    const int ss = blockIdx.y;            // 8 support chunks of 512

    for (int i = tid; i < 128 * NCLS; i += 256) ((float*)NumS)[i] = 0.f;

    // Q fragments for this wave's 2x16 rows (A-layout m = c16), full K=512
    f16x8 qf[2][16];
#pragma unroll
    for (int h = 0; h < 2; ++h) {
        const f16* qb = E + (size_t)(N_SUP + qt * 128 + h * 64 + w * 16 + c16) * EMB + q * 8;
#pragma unroll
        for (int ks = 0; ks < 16; ++ks) qf[h][ks] = *(const f16x8*)(qb + ks * 32);
    }
    float q2[2][4];
#pragma unroll
    for (int h = 0; h < 2; ++h)
#pragma unroll
        for (int r = 0; r < 4; ++r)
            q2[h][r] = norms[N_SUP + qt * 128 + h * 64 + w * 16 + q * 4 + r];

    float den[2][4] = {};
    const int sr = tid >> 2;              // 0..63
    const int koff0 = (tid & 3) * 8;      // 0,8,16,24

    for (int s0 = ss * 512; s0 < ss * 512 + 512; s0 += 64) {
        f32x4 acc[2][4];
#pragma unroll
        for (int h = 0; h < 2; ++h)
#pragma unroll
            for (int nb = 0; nb < 4; ++nb) acc[h][nb] = (f32x4){0.f, 0.f, 0.f, 0.f};

        const f16* srcrow = E + (size_t)(s0 + sr) * EMB;
#pragma unroll
        for (int kc = 0; kc < 4; ++kc) {
            __syncthreads();
#pragma unroll
            for (int i = 0; i < 4; ++i) {
                int koff = koff0 + i * 32;
                *(f16x8*)&Ss[sr][koff] = *(const f16x8*)(srcrow + kc * 128 + koff);
            }
            __syncthreads();
#pragma unroll
            for (int ksl = 0; ksl < 4; ++ksl) {
#pragma unroll
                for (int nb = 0; nb < 4; ++nb) {
                    f16x8 b = *(const f16x8*)&Ss[nb * 16 + c16][ksl * 32 + q * 8];
                    acc[0][nb] = __builtin_amdgcn_mfma_f32_16x16x32_f16(qf[0][kc * 4 + ksl], b, acc[0][nb], 0, 0, 0);
                    acc[1][nb] = __builtin_amdgcn_mfma_f32_16x16x32_f16(qf[1][kc * 4 + ksl], b, acc[1][nb], 0, 0, 0);
                }
            }
        }
        // epilogue: exp(-sqrt(d2)), denominator, label scatter into LDS
#pragma unroll
        for (int nb = 0; nb < 4; ++nb) {
            int col = s0 + nb * 16 + c16;
            float s2 = norms[col];
            int lb = lbl[col];
#pragma unroll
            for (int h = 0; h < 2; ++h) {
#pragma unroll
                for (int r = 0; r < 4; ++r) {
                    float d2 = fmaxf(q2[h][r] + s2 - 2.f * acc[h][nb][r], 0.f);
                    float e = __expf(-sqrtf(d2));
                    den[h][r] += e;
                    atomicAdd(&NumS[h * 64 + w * 16 + q * 4 + r][lb], e);
                }
            }
        }
    }

#pragma unroll
    for (int h = 0; h < 2; ++h)
#pragma unroll
        for (int r = 0; r < 4; ++r) {
            float v = den[h][r];
            v += __shfl_xor(v, 1); v += __shfl_xor(v, 2);
            v += __shfl_xor(v, 4); v += __shfl_xor(v, 8);
            if (c16 == 0)
                atomicAdd(&Den[qt * 128 + h * 64 + w * 16 + q * 4 + r], v);
        }
    __syncthreads();
    for (int i = tid; i < 128 * NCLS; i += 256)
        atomicAdd(&Num[(size_t)qt * 128 * NCLS + i], ((float*)NumS)[i]);
}

// ---- finalize: out = fp32(Num/Den) ----
__global__ void finalize(const float* __restrict__ Num, const float* __restrict__ Den,
                         float* __restrict__ out) {
    int i = blockIdx.x * 256 + threadIdx.x;
    if (i >= N_QRY * NCLS) return;
    out[i] = Num[i] / Den[i >> 6];
}

extern "C" void kernel_launch(void* const* d_in, const int* in_sizes, int n_in,
                              void* d_out, int out_size, void* d_ws, size_t ws_size,
                              hipStream_t stream) {
    (void)in_sizes; (void)n_in; (void)out_size; (void)ws_size;
    const float* sup  = (const float*)d_in[0];
    const float* qry  = (const float*)d_in[1];
    const float* lab  = (const float*)d_in[2];
    const float* Wenc = (const float*)d_in[3];
    const float* benc = (const float*)d_in[4];
    float* out = (float*)d_out;

    char* ws = (char*)d_ws;
    size_t off = 0;
    f16* WT = (f16*)(ws + off);        off += (size_t)EMB * IN_DIM * 2;   // 802816
    f16* E  = (f16*)(ws + off);        off += (size_t)M_TOT * EMB * 2;    // 12582912
    float* norms = (float*)(ws + off); off += (size_t)M_TOT * 4;          // 49152
    int* lbl = (int*)(ws + off);       off += (size_t)N_SUP * 4;          // 16384
    float* Num = (float*)(ws + off);   off += (size_t)N_QRY * NCLS * 4;   // 2097152
    float* Den = (float*)(ws + off);   off += (size_t)N_QRY * 4;          // 32768

    hipMemsetAsync(norms, 0, (size_t)M_TOT * 4, stream);
    hipMemsetAsync(Num, 0, (size_t)N_QRY * NCLS * 4 + (size_t)N_QRY * 4, stream);

    prep_wt<<<dim3(25, 16), 256, 0, stream>>>(Wenc, WT);
    prep_lbl<<<(N_SUP + 255) / 256, 256, 0, stream>>>(lab, lbl);
    encode<<<dim3(M_TOT / 128, EMB / 128), 256, 0, stream>>>(sup, qry, WT, benc, E, norms);
    attn<<<dim3(N_QRY / 128, 8), 256, 0, stream>>>(E, norms, lbl, Num, Den);
    finalize<<<(N_QRY * NCLS + 255) / 256, 256, 0, stream>>>(Num, Den, out);
}

// Round 5
// 236.761 us; speedup vs baseline: 1.8286x; 1.4636x over previous
//
#include <hip/hip_runtime.h>

#define N_SUP 4096
#define N_QRY 8192
#define IN_DIM 784
#define EMB 512
#define NCLS 64
#define M_TOT (N_SUP + N_QRY)

typedef _Float16 f16;
typedef _Float16 f16x8 __attribute__((ext_vector_type(8)));
typedef float f32x4 __attribute__((ext_vector_type(4)));

// load 8 consecutive fp32 and convert to f16x8
static __device__ __forceinline__ f16x8 cvt8(const float* p) {
    float4 a = *(const float4*)p;
    float4 b = *(const float4*)(p + 4);
    f16x8 v;
    v[0] = (f16)a.x; v[1] = (f16)a.y; v[2] = (f16)a.z; v[3] = (f16)a.w;
    v[4] = (f16)b.x; v[5] = (f16)b.y; v[6] = (f16)b.z; v[7] = (f16)b.w;
    return v;
}

// ---- prep: W (784x512 fp32) -> WT (512x784 f16), LDS-tiled transpose ----
__global__ __launch_bounds__(256) void prep_wt(const float* __restrict__ W,
                                               f16* __restrict__ WT) {
    __shared__ float T[32][33];
    const int k0 = blockIdx.x * 32, n0 = blockIdx.y * 32;
    const int tx = threadIdx.x & 31, ty = threadIdx.x >> 5;
#pragma unroll
    for (int i = 0; i < 4; ++i) {
        int k = k0 + ty + i * 8;
        T[ty + i * 8][tx] = (k < IN_DIM) ? W[(size_t)k * EMB + n0 + tx] : 0.f;
    }
    __syncthreads();
#pragma unroll
    for (int i = 0; i < 4; ++i) {
        int n = n0 + ty + i * 8;
        int k = k0 + tx;
        if (k < IN_DIM) WT[(size_t)n * IN_DIM + k] = (f16)T[tx][ty + i * 8];
    }
}

// ---- prep: one-hot labels (4096x64 fp32) -> argmax index ----
__global__ void prep_lbl(const float* __restrict__ lab, int* __restrict__ lbl) {
    int s = blockIdx.x * 256 + threadIdx.x;
    if (s >= N_SUP) return;
    int best = 0; float bv = -1e30f;
    for (int c = 0; c < NCLS; ++c) {
        float v = lab[s * NCLS + c];
        if (v > bv) { bv = v; best = c; }
    }
    lbl[s] = best;
}

// ---- prep: Lcs[c][s] = one-hot transpose (64 x 4096 f16) ----
__global__ void prep_L(const int* __restrict__ lbl, f16* __restrict__ Lcs) {
    int idx = blockIdx.x * 256 + threadIdx.x;
    if (idx >= NCLS * N_SUP) return;
    int c = idx >> 12, s = idx & (N_SUP - 1);
    Lcs[idx] = (lbl[s] == c) ? (f16)1.f : (f16)0.f;
}

// ---- encode: E = X @ W + b, 128x64 tile (grid 96x8 = 768 blocks, 3/CU) ----
__global__ __launch_bounds__(256) void encode(
    const float* __restrict__ sup, const float* __restrict__ qry,
    const f16* __restrict__ WT, const float* __restrict__ bias,
    f16* __restrict__ E, float* __restrict__ norms)
{
    __shared__ __align__(16) f16 Xs[128][40];
    __shared__ __align__(16) f16 Ws[64][40];
    const int tid = threadIdx.x;
    const int w = tid >> 6, lane = tid & 63;
    const int q = lane >> 4, c16 = lane & 15;
    const int m0 = blockIdx.x * 128, n0 = blockIdx.y * 64;

    f32x4 acc[2][4];
#pragma unroll
    for (int h = 0; h < 2; ++h)
#pragma unroll
        for (int nb = 0; nb < 4; ++nb) acc[h][nb] = (f32x4){0.f, 0.f, 0.f, 0.f};

    const int sr = tid >> 2;
    const int koff = (tid & 3) * 8;
    const float *xrow0, *xrow1;
    {
        int g0 = m0 + sr, g1 = m0 + sr + 64;
        xrow0 = (g0 < N_SUP) ? sup + (size_t)g0 * IN_DIM : qry + (size_t)(g0 - N_SUP) * IN_DIM;
        xrow1 = (g1 < N_SUP) ? sup + (size_t)g1 * IN_DIM : qry + (size_t)(g1 - N_SUP) * IN_DIM;
    }
    const f16* wrow = WT + (size_t)(n0 + sr) * IN_DIM;

    for (int k0 = 0; k0 < IN_DIM; k0 += 32) {
        __syncthreads();
        if (k0 + koff + 8 <= IN_DIM) {
            *(f16x8*)&Xs[sr][koff]      = cvt8(xrow0 + k0 + koff);
            *(f16x8*)&Xs[sr + 64][koff] = cvt8(xrow1 + k0 + koff);
            *(f16x8*)&Ws[sr][koff]      = *(const f16x8*)(wrow + k0 + koff);
        } else {
            f16x8 z = (f16x8){0,0,0,0,0,0,0,0};
            *(f16x8*)&Xs[sr][koff]      = z;
            *(f16x8*)&Xs[sr + 64][koff] = z;
            *(f16x8*)&Ws[sr][koff]      = z;
        }
        __syncthreads();
        f16x8 a0 = *(const f16x8*)&Xs[w * 16 + c16][q * 8];
        f16x8 a1 = *(const f16x8*)&Xs[64 + w * 16 + c16][q * 8];
#pragma unroll
        for (int nb = 0; nb < 4; ++nb) {
            f16x8 b = *(const f16x8*)&Ws[nb * 16 + c16][q * 8];
            acc[0][nb] = __builtin_amdgcn_mfma_f32_16x16x32_f16(a0, b, acc[0][nb], 0, 0, 0);
            acc[1][nb] = __builtin_amdgcn_mfma_f32_16x16x32_f16(a1, b, acc[1][nb], 0, 0, 0);
        }
    }

    float nrm[2][4] = {};
#pragma unroll
    for (int nb = 0; nb < 4; ++nb) {
        int col = n0 + nb * 16 + c16;
        float bv = bias[col];
#pragma unroll
        for (int h = 0; h < 2; ++h)
#pragma unroll
            for (int r = 0; r < 4; ++r) {
                int row = m0 + h * 64 + w * 16 + q * 4 + r;
                float v = acc[h][nb][r] + bv;
                E[(size_t)row * EMB + col] = (f16)v;
                nrm[h][r] += v * v;
            }
    }
#pragma unroll
    for (int h = 0; h < 2; ++h)
#pragma unroll
        for (int r = 0; r < 4; ++r) {
            float v = nrm[h][r];
            v += __shfl_xor(v, 1); v += __shfl_xor(v, 2);
            v += __shfl_xor(v, 4); v += __shfl_xor(v, 8);
            if (c16 == 0) atomicAdd(&norms[m0 + h * 64 + w * 16 + q * 4 + r], v);
        }
}

// ---- anchor: m[q] = d(query q, support 0) — global softmax shift ----
__global__ __launch_bounds__(256) void anchor(const f16* __restrict__ E,
                                              const float* __restrict__ norms,
                                              float* __restrict__ manc) {
    __shared__ float s0e[EMB];
    const int tid = threadIdx.x;
    s0e[tid] = (float)E[tid];
    s0e[tid + 256] = (float)E[tid + 256];
    __syncthreads();
    const int qrow = blockIdx.x * 256 + tid;
    const f16* qp = E + (size_t)(N_SUP + qrow) * EMB;
    float dot = 0.f;
    for (int k = 0; k < EMB; k += 8) {
        f16x8 v = *(const f16x8*)(qp + k);
#pragma unroll
        for (int j = 0; j < 8; ++j) dot += (float)v[j] * s0e[k + j];
    }
    float d2 = fmaxf(norms[N_SUP + qrow] + norms[0] - 2.f * dot, 0.f);
    manc[qrow] = sqrtf(d2);
}

// ---- attn: QK-dist -> p=exp(m-d) -> P*onehot(L) via MFMA. No LDS atomics.
// q-tile 64 (1 A-frag set/wave), S double-buffered, 1 barrier/chunk.
__global__ __launch_bounds__(256, 3) void attn(
    const f16* __restrict__ E, const float* __restrict__ norms,
    const float* __restrict__ manc, const f16* __restrict__ Lcs,
    float* __restrict__ Num)
{
    __shared__ __align__(16) f16 Ss[2][64][136];
    __shared__ __align__(16) f16 Pt[4][16][72];   // per-wave P transpose buffer
    const int tid = threadIdx.x;
    const int w = tid >> 6, lane = tid & 63;
    const int q = lane >> 4, c16 = lane & 15;
    const int qt = blockIdx.x, ss = blockIdx.y;

    // resident Q fragments (A-layout m=c16): 16 x f16x8 = 64 VGPRs
    f16x8 qf[16];
    const f16* qb = E + (size_t)(N_SUP + qt * 64 + w * 16 + c16) * EMB + q * 8;
#pragma unroll
    for (int ks = 0; ks < 16; ++ks) qf[ks] = *(const f16x8*)(qb + ks * 32);
    float q2[4], mrow[4];
#pragma unroll
    for (int r = 0; r < 4; ++r) {
        q2[r]   = norms[N_SUP + qt * 64 + w * 16 + q * 4 + r];
        mrow[r] = manc[qt * 64 + w * 16 + q * 4 + r];
    }

    f32x4 accPL[4];
#pragma unroll
    for (int nb = 0; nb < 4; ++nb) accPL[nb] = (f32x4){0.f, 0.f, 0.f, 0.f};

    const int sr = tid >> 2, koff0 = (tid & 3) * 8;
    const f16* sbase = E + (size_t)(ss * 512 + sr) * EMB;

    // prologue: stage chunk 0 (it=0, kc=0)
    f16x8 g[4];
#pragma unroll
    for (int i = 0; i < 4; ++i) g[i] = *(const f16x8*)(sbase + koff0 + i * 32);
#pragma unroll
    for (int i = 0; i < 4; ++i) *(f16x8*)&Ss[0][sr][koff0 + i * 32] = g[i];
    __syncthreads();

    for (int it = 0; it < 8; ++it) {
        f32x4 accQK[4];
#pragma unroll
        for (int nb = 0; nb < 4; ++nb) accQK[nb] = (f32x4){0.f, 0.f, 0.f, 0.f};
#pragma unroll
        for (int kc = 0; kc < 4; ++kc) {
            const int idx = it * 4 + kc;
            const int cur = idx & 1;
            if (idx + 1 < 32) {   // prefetch next chunk: overlap with compute below
                const int nit = (idx + 1) >> 2, nkc = (idx + 1) & 3;
                const f16* src = sbase + (size_t)(nit * 64) * EMB + nkc * 128 + koff0;
#pragma unroll
                for (int i = 0; i < 4; ++i) g[i] = *(const f16x8*)(src + i * 32);
            }
#pragma unroll
            for (int ksl = 0; ksl < 4; ++ksl) {
#pragma unroll
                for (int nb = 0; nb < 4; ++nb) {
                    f16x8 b = *(const f16x8*)&Ss[cur][nb * 16 + c16][ksl * 32 + q * 8];
                    accQK[nb] = __builtin_amdgcn_mfma_f32_16x16x32_f16(qf[kc * 4 + ksl], b, accQK[nb], 0, 0, 0);
                }
            }
            if (idx + 1 < 32) {
#pragma unroll
                for (int i = 0; i < 4; ++i) *(f16x8*)&Ss[cur ^ 1][sr][koff0 + i * 32] = g[i];
            }
            __syncthreads();
        }
        // epilogue: p = exp(m - d), wave-private LDS transpose, P*L MFMA
        const int s0g = ss * 512 + it * 64;
#pragma unroll
        for (int nb = 0; nb < 4; ++nb) {
            const int col = s0g + nb * 16 + c16;
            const float s2 = norms[col];
#pragma unroll
            for (int r = 0; r < 4; ++r) {
                float d2 = fmaxf(q2[r] + s2 - 2.f * accQK[nb][r], 0.f);
                float p = __expf(mrow[r] - sqrtf(d2));
                p = fminf(p, 60000.f);     // f16-overflow guard (≥10σ tail only)
                Pt[w][q * 4 + r][nb * 16 + c16] = (f16)p;
            }
        }
#pragma unroll
        for (int kc2 = 0; kc2 < 2; ++kc2) {
            f16x8 af = *(const f16x8*)&Pt[w][c16][kc2 * 32 + q * 8];
#pragma unroll
            for (int nbc = 0; nbc < 4; ++nbc) {
                f16x8 bl = *(const f16x8*)(Lcs + (size_t)(nbc * 16 + c16) * N_SUP + s0g + kc2 * 32 + q * 8);
                accPL[nbc] = __builtin_amdgcn_mfma_f32_16x16x32_f16(af, bl, accPL[nbc], 0, 0, 0);
            }
        }
    }
    // flush Num partials (8 ss-chunks contend via global f32 atomics)
#pragma unroll
    for (int nbc = 0; nbc < 4; ++nbc)
#pragma unroll
        for (int r = 0; r < 4; ++r)
            atomicAdd(&Num[(size_t)(qt * 64 + w * 16 + q * 4 + r) * NCLS + nbc * 16 + c16],
                      accPL[nbc][r]);
}

// ---- finalize: out[q][c] = Num[q][c] / rowsum(Num[q]) ----
__global__ __launch_bounds__(256) void finalize(const float* __restrict__ Num,
                                                float* __restrict__ out) {
    const int tid = threadIdx.x;
    const int w = tid >> 6, lane = tid & 63;
    const int qrow = blockIdx.x * 4 + w;
    float v = Num[(size_t)qrow * NCLS + lane];
    float s = v;
    s += __shfl_xor(s, 1);  s += __shfl_xor(s, 2);  s += __shfl_xor(s, 4);
    s += __shfl_xor(s, 8);  s += __shfl_xor(s, 16); s += __shfl_xor(s, 32);
    out[(size_t)qrow * NCLS + lane] = v / s;
}

extern "C" void kernel_launch(void* const* d_in, const int* in_sizes, int n_in,
                              void* d_out, int out_size, void* d_ws, size_t ws_size,
                              hipStream_t stream) {
    (void)in_sizes; (void)n_in; (void)out_size; (void)ws_size;
    const float* sup  = (const float*)d_in[0];
    const float* qry  = (const float*)d_in[1];
    const float* lab  = (const float*)d_in[2];
    const float* Wenc = (const float*)d_in[3];
    const float* benc = (const float*)d_in[4];
    float* out = (float*)d_out;

    char* ws = (char*)d_ws;
    size_t off = 0;
    f16* WT = (f16*)(ws + off);        off += (size_t)EMB * IN_DIM * 2;   // 802816
    f16* E  = (f16*)(ws + off);        off += (size_t)M_TOT * EMB * 2;    // 12582912
    float* norms = (float*)(ws + off); off += (size_t)M_TOT * 4;          // 49152
    int* lbl = (int*)(ws + off);       off += (size_t)N_SUP * 4;          // 16384
    f16* Lcs = (f16*)(ws + off);       off += (size_t)NCLS * N_SUP * 2;   // 524288
    float* manc = (float*)(ws + off);  off += (size_t)N_QRY * 4;          // 32768
    float* Num = (float*)(ws + off);   off += (size_t)N_QRY * NCLS * 4;   // 2097152

    hipMemsetAsync(norms, 0, (size_t)M_TOT * 4, stream);
    hipMemsetAsync(Num, 0, (size_t)N_QRY * NCLS * 4, stream);

    prep_wt<<<dim3(25, 16), 256, 0, stream>>>(Wenc, WT);
    prep_lbl<<<(N_SUP + 255) / 256, 256, 0, stream>>>(lab, lbl);
    prep_L<<<(NCLS * N_SUP + 255) / 256, 256, 0, stream>>>(lbl, Lcs);
    encode<<<dim3(M_TOT / 128, EMB / 64), 256, 0, stream>>>(sup, qry, WT, benc, E, norms);
    anchor<<<N_QRY / 256, 256, 0, stream>>>(E, norms, manc);
    attn<<<dim3(N_QRY / 64, 8), 256, 0, stream>>>(E, norms, manc, Lcs, Num);
    finalize<<<N_QRY / 4, 256, 0, stream>>>(Num, out);
}